// Round 5
// baseline (407.859 us; speedup 1.0000x reference)
//
#include <hip/hip_runtime.h>
#include <math.h>

// ---------------- Workspace layout ----------------
// floats:   [0, 40960)        td accumulator (4096 x 10)
//           [40960, 81920)    Wtdr[tt][j][row][k] reordered W_td
//           [81920, 122880)   sc accumulator (4096 x 10)
// bytes:    [524288, +166*8192)  Bg: bf16 hi/lo B slabs in MFMA-fragment
//           order, Bg[s][plane][n][16k]; slab 8192 B; 162 real + pad slabs
#define TD_OFF 0
#define WTDR_OFF 40960
#define SC_OFF 81920
#define BG_BYTE_OFF 524288

typedef __bf16 bf16x8 __attribute__((ext_vector_type(8)));
typedef float f32x16 __attribute__((ext_vector_type(16)));
typedef float f32x2 __attribute__((ext_vector_type(2)));

union FragU { bf16x8 v; float4 f; };

__device__ __forceinline__ f32x16 mfma16(bf16x8 a, bf16x8 b, f32x16 c) {
    return __builtin_amdgcn_mfma_f32_32x32x16_bf16(a, b, c, 0, 0, 0);
}

__device__ __forceinline__ float eluf(float v) {
    return v > 0.f ? v : __expf(v) - 1.f;
}

// ---------------- prep: Wtdr reorder + Bg build ----------------------------
__global__ __launch_bounds__(256) void prep(const float* __restrict__ dw,
                                            const float* __restrict__ pw,
                                            const float* __restrict__ Wtd,
                                            float* __restrict__ Wtdr,
                                            unsigned short* __restrict__ Bg) {
    int gid = blockIdx.x * 256 + threadIdx.x;
    if (gid < 40960) {
        int k = gid & 3;
        int r = gid >> 2;
        int row = r & 31; r >>= 5;
        int j = r % 10;
        int tt = r / 10;
        Wtdr[gid] = Wtd[(size_t)(row * 128 + tt * 4 + k) * 10 + j];
        return;
    }
    int g2 = gid - 40960;
    if (g2 >= 162 * 128) return;
    int n = g2 & 127;
    int s = g2 >> 7;
    int half = s & 1;
    int cd = s >> 1;
    int c = cd / 27, d = cd % 27;
    int w = n >> 2, f = n & 3;
    unsigned short* dsth = Bg + (size_t)s * 4096 + n * 16;   // ushort units
    unsigned short* dstl = dsth + 2048;
#pragma unroll
    for (int k = 0; k < 16; k++) {
        int xi = half * 16 + k;
        int dx = xi - w + 13;
        float v = 0.f;
        if (dx >= 0 && dx < 27) {
#pragma unroll
            for (int m = 0; m < 5; m++)
                v = fmaf(dw[((d * 27 + dx) * 3 + c) * 5 + m],
                         pw[(c * 5 + m) * 4 + f], v);
        }
        __bf16 h = (__bf16)v;
        __bf16 l = (__bf16)(v - (float)h);
        dsth[k] = __builtin_bit_cast(unsigned short, h);
        dstl[k] = __builtin_bit_cast(unsigned short, l);
    }
}

// ---------------- fused: conv (MFMA pipe) + lstm (VALU pipe) co-scheduled --
// blockIdx % 5 == 4  -> lstm block (512 total)
// else               -> conv block (2048 total, 2 images each)
// I=2 images/block: LDS 24.9 KB -> 5 blocks/CU (launch_bounds(256,5),
// VGPR<=102) = 20 waves/CU vs r4's 12. A-LDS reads/staging/MFMA totals are
// I-invariant; only B-L2 doubles (2.65 GB ~ 31% of L2 ceiling, depth-3
// prefetched). Attacks the latency-bound 26%-occupancy regime directly.
#define A_OFF 0
#define ZOFF 24576           /* 16 B zeros */
#define SRED_OFF 24592       /* 4 waves * 2 img * 10 floats = 320 B */
#define LDS_BYTES 24912

__global__ __launch_bounds__(256, 5) void fused(const float* __restrict__ x,
                                                const float* __restrict__ W,
                                                const float* __restrict__ U,
                                                const float* __restrict__ Wtdr,
                                                const unsigned short* __restrict__ Bg,
                                                const float* __restrict__ Wsc,
                                                const float* __restrict__ bias,
                                                float* __restrict__ td_out,
                                                float* __restrict__ sc_out) {
    __shared__ char LDS[LDS_BYTES] __attribute__((aligned(16)));
    int bx = blockIdx.x;
    int rem = bx % 5;
    int q = bx / 5;
    int t = threadIdx.x;

    if (rem == 4) {
        // ================= LSTM branch (block q in [0,512)) =================
        f32x2 sW0[8], sW1[8], sW2[8], sU0[8], sU1[8], sU2[8], sU3[8];
        const f32x2* Wp = (const f32x2*)W;
        const f32x2* Up = (const f32x2*)U;
#pragma unroll
        for (int k2 = 0; k2 < 8; k2++) {
            sW0[k2] = Wp[k2];
            sW1[k2] = Wp[8 + k2];
            sW2[k2] = Wp[16 + k2];
            sU0[k2] = Up[k2];
            sU1[k2] = Up[8 + k2];
            sU2[k2] = Up[16 + k2];
            sU3[k2] = Up[24 + k2];
        }

        int n = q * 256 + t;   // n = b*32 + row
        int row = n & 31;
        const float4* xp4 = (const float4*)(x + (size_t)n * 96);

        float h0 = 0, h1 = 0, h2 = 0, h3 = 0;
        float c0 = 0, c1 = 0, c2 = 0, c3 = 0;
        f32x2 pa2[10];
#pragma unroll
        for (int j = 0; j < 10; j++) pa2[j] = 0.f;

        for (int g = 0; g < 8; g++) {
            float4 q0 = xp4[g * 3 + 0], q1 = xp4[g * 3 + 1], q2 = xp4[g * 3 + 2];
            float xr[12] = {q0.x, q0.y, q0.z, q0.w, q1.x, q1.y,
                            q1.z, q1.w, q2.x, q2.y, q2.z, q2.w};
#pragma unroll
            for (int st = 0; st < 4; st++) {
                int tt = g * 4 + st;
                float x0 = xr[st * 3 + 0], x1 = xr[st * 3 + 1], x2 = xr[st * 3 + 2];
                f32x2 z2[8];
#pragma unroll
                for (int k2 = 0; k2 < 8; k2++)
                    z2[k2] = sW0[k2] * x0 + sW1[k2] * x1 + sW2[k2] * x2
                           + sU0[k2] * h0 + sU1[k2] * h1 + sU2[k2] * h2
                           + sU3[k2] * h3;

                float ig0 = eluf(z2[0][0]), ig1 = eluf(z2[0][1]);
                float ig2 = eluf(z2[1][0]), ig3 = eluf(z2[1][1]);
                float fg0 = eluf(z2[2][0]), fg1 = eluf(z2[2][1]);
                float fg2 = eluf(z2[3][0]), fg3 = eluf(z2[3][1]);
                float og0 = eluf(z2[6][0]), og1 = eluf(z2[6][1]);
                float og2 = eluf(z2[7][0]), og3 = eluf(z2[7][1]);

                float zc0 = z2[4][0], zc1 = z2[4][1], zc2 = z2[5][0], zc3 = z2[5][1];
                float zm = fmaxf(fmaxf(zc0, zc1), fmaxf(zc2, zc3));
                float e0 = __expf(zc0 - zm), e1 = __expf(zc1 - zm);
                float e2 = __expf(zc2 - zm), e3 = __expf(zc3 - zm);
                float inv = 1.f / (e0 + e1 + e2 + e3);
                c0 = fg0 * c0 + ig0 * (e0 * inv);
                c1 = fg1 * c1 + ig1 * (e1 * inv);
                c2 = fg2 * c2 + ig2 * (e2 * inv);
                c3 = fg3 * c3 + ig3 * (e3 * inv);

                float cm = fmaxf(fmaxf(c0, c1), fmaxf(c2, c3));
                float p0 = __expf(c0 - cm), p1 = __expf(c1 - cm);
                float p2 = __expf(c2 - cm), p3 = __expf(c3 - cm);
                float pinv = 1.f / (p0 + p1 + p2 + p3);
                h0 = og0 * (p0 * pinv); h1 = og1 * (p1 * pinv);
                h2 = og2 * (p2 * pinv); h3 = og3 * (p3 * pinv);

                const f32x2* wr2 = (const f32x2*)(Wtdr + (size_t)tt * 1280) + row * 2;
                f32x2 h01 = {h0, h1}, h23 = {h2, h3};
#pragma unroll
                for (int j = 0; j < 10; j++)
                    pa2[j] += h01 * wr2[j * 64] + h23 * wr2[j * 64 + 1];
            }
        }

        float acc[10];
#pragma unroll
        for (int j = 0; j < 10; j++) acc[j] = pa2[j][0] + pa2[j][1];
#pragma unroll
        for (int off = 16; off >= 1; off >>= 1) {
#pragma unroll
            for (int j = 0; j < 10; j++) acc[j] += __shfl_xor(acc[j], off, 64);
        }
        int lane = t & 63;
        if (lane == 0 || lane == 32) {
            int b = n >> 5;
#pragma unroll
            for (int j = 0; j < 10; j++) td_out[b * 10 + j] = acc[j];
        }
        return;
    }

    // ================= conv branch (ci in [0,2048), 2 images) ==============
    int ci = q * 4 + rem;
    int l = t & 63;
    int wv = t >> 6;           // wave owns ntile = wv, both images
    int m = l & 31;
    int sub = l >> 5;          // k-subgroup (8 k's each)

    const char* bbase = (const char*)Bg + (size_t)wv * 1024 + m * 32 + sub * 16;
    FragU bufA[2], bufB[2], bufC[2];
#define LOADB(sv, arr) { const char* p_ = bbase + (size_t)(sv) * 8192;       \
        arr[0].f = *(const float4*)(p_);          /* hi */                   \
        arr[1].f = *(const float4*)(p_ + 4096); } /* lo */

    LOADB(0, bufA);
    LOADB(1, bufB);
    LOADB(2, bufC);

    // ---- stage A: thread <-> (img, w-oct, h); b128 writes, conflict-free --
    const float* xb = x + (size_t)ci * 6144;
    {
        int u = t;                       // 256 units: 2 img x 4 woct x 32 h
        int im = u >> 7;
        int woct = (u >> 5) & 3;
        int h = u & 31;
        const float4* src = (const float4*)(xb + im * 3072 + h * 96 + woct * 24);
        float xr[24];
#pragma unroll
        for (int i = 0; i < 6; i++) {
            float4 qv = src[i];
            xr[i * 4 + 0] = qv.x; xr[i * 4 + 1] = qv.y;
            xr[i * 4 + 2] = qv.z; xr[i * 4 + 3] = qv.w;
        }
#pragma unroll
        for (int cc = 0; cc < 3; cc++) {
            FragU hiF, loF;
#pragma unroll
            for (int k = 0; k < 8; k++) {
                float v = xr[k * 3 + cc];
                __bf16 hb = (__bf16)v;
                hiF.v[k] = hb;
                loF.v[k] = (__bf16)(v - (float)hb);
            }
            int rec = A_OFF + im * 12288 + (cc * 8 + woct) * 512 + h * 16;
            *(float4*)(LDS + rec) = hiF.f;
            *(float4*)(LDS + rec + 2048) = loF.f;
        }
    }
    if (t < 4) *(float*)(LDS + ZOFF + t * 4) = 0.f;
    __syncthreads();   // the only barrier before the epilogue

    f32x16 acc0 = {0,0,0,0,0,0,0,0,0,0,0,0,0,0,0,0};
    f32x16 acc1 = acc0;

    int c = 0, d = 0, half = 0;

#define CHUNK(USE, SNEXT) {                                                   \
    int rowIdx = m + d - 13;                                                  \
    bool valid = (unsigned)rowIdx < 32u;                                      \
    int a0 = A_OFF + (c * 8 + half * 2 + sub) * 512 + rowIdx * 16;            \
    FragU ah0, ah1, al0, al1;                                                 \
    ah0.f = *(const float4*)(LDS + (valid ? a0           : ZOFF));            \
    ah1.f = *(const float4*)(LDS + (valid ? a0 + 12288   : ZOFF));            \
    al0.f = *(const float4*)(LDS + (valid ? a0 + 2048    : ZOFF));            \
    al1.f = *(const float4*)(LDS + (valid ? a0 + 14336   : ZOFF));            \
    acc0 = mfma16(ah0.v, USE[0].v, acc0);                                     \
    acc1 = mfma16(ah1.v, USE[0].v, acc1);                                     \
    acc0 = mfma16(ah0.v, USE[1].v, acc0);                                     \
    acc1 = mfma16(ah1.v, USE[1].v, acc1);                                     \
    acc0 = mfma16(al0.v, USE[0].v, acc0);                                     \
    acc1 = mfma16(al1.v, USE[0].v, acc1);                                     \
    LOADB(SNEXT, USE);                                                        \
    half ^= 1;                                                                \
    if (!half) { d++; if (d == 27) { d = 0; c++; } }                          \
}

    for (int g = 0; g < 54; g++) {
        CHUNK(bufA, 3 * g + 3);
        CHUNK(bufB, 3 * g + 4);
        CHUNK(bufC, 3 * g + 5);
    }

    // ---- epilogue: bias + sigmoid + W_sc partial dot (rows reused x2) ----
    float b4[4];
#pragma unroll
    for (int i = 0; i < 4; i++) b4[i] = bias[i];

    float part[2][10];
#pragma unroll
    for (int i = 0; i < 2; i++)
#pragma unroll
        for (int j = 0; j < 10; j++) part[i][j] = 0.f;

    f32x16 accs[2] = {acc0, acc1};
    int ncol = wv * 32 + m;
    int wcol = ncol >> 2;
    int f = ncol & 3;
#pragma unroll
    for (int r = 0; r < 16; r++) {
        int h = (r & 3) + 8 * (r >> 2) + 4 * sub;
        const float* wr = Wsc + (size_t)((h * 32 + wcol) * 4 + f) * 10;
        float wreg[10];
#pragma unroll
        for (int j = 0; j < 10; j++) wreg[j] = wr[j];
#pragma unroll
        for (int im = 0; im < 2; im++) {
            float v = accs[im][r] + b4[f];
            float sg = 1.f / (1.f + __expf(-v));
#pragma unroll
            for (int j = 0; j < 10; j++) part[im][j] = fmaf(sg, wreg[j], part[im][j]);
        }
    }

#pragma unroll
    for (int off = 32; off >= 1; off >>= 1) {
#pragma unroll
        for (int im = 0; im < 2; im++)
#pragma unroll
            for (int j = 0; j < 10; j++) part[im][j] += __shfl_xor(part[im][j], off, 64);
    }
    if (l == 0) {
        float* red = (float*)(LDS + SRED_OFF);
#pragma unroll
        for (int im = 0; im < 2; im++)
#pragma unroll
            for (int j = 0; j < 10; j++) red[(wv * 2 + im) * 10 + j] = part[im][j];
    }
    __syncthreads();
    if (t < 20) {
        int img = t / 10, j = t % 10;
        const float* red = (const float*)(LDS + SRED_OFF);
        float sv = red[(0 * 2 + img) * 10 + j] + red[(1 * 2 + img) * 10 + j]
                 + red[(2 * 2 + img) * 10 + j] + red[(3 * 2 + img) * 10 + j];
        sc_out[(ci * 2 + img) * 10 + j] = sv;
    }
}

// ---------------- compare: |td - sc| <= atol + rtol*|sc| -------------------
__global__ __launch_bounds__(256) void cmp_k(const float* __restrict__ td,
                                             const float* __restrict__ sc,
                                             float* __restrict__ out) {
    int i = blockIdx.x * 256 + threadIdx.x;
    if (i < 40960) {
        float a = td[i];
        float s = sc[i];
        float tol = 1e-6f + 1e-6f * fabsf(s);
        out[i] = (fabsf(a - s) <= tol) ? 1.0f : 0.0f;
    }
}

extern "C" void kernel_launch(void* const* d_in, const int* in_sizes, int n_in,
                              void* d_out, int out_size, void* d_ws, size_t ws_size,
                              hipStream_t stream) {
    const float* x    = (const float*)d_in[0];
    const float* W    = (const float*)d_in[1];
    const float* U    = (const float*)d_in[2];
    const float* dw   = (const float*)d_in[3];
    const float* pw   = (const float*)d_in[4];
    const float* bias = (const float*)d_in[5];
    const float* Wtd  = (const float*)d_in[6];
    const float* Wsc  = (const float*)d_in[7];

    float* ws     = (float*)d_ws;
    float* td_acc = ws + TD_OFF;
    float* Wtdr   = ws + WTDR_OFF;
    float* sc_acc = ws + SC_OFF;
    unsigned short* Bg = (unsigned short*)((char*)d_ws + BG_BYTE_OFF);

    prep<<<241, 256, 0, stream>>>(dw, pw, Wtd, Wtdr, Bg);
    fused<<<2560, 256, 0, stream>>>(x, W, U, Wtdr, Bg, Wsc, bias, td_acc, sc_acc);
    cmp_k<<<160, 256, 0, stream>>>(td_acc, sc_acc, (float*)d_out);
}

// Round 6
// 393.617 us; speedup vs baseline: 1.0362x; 1.0362x over previous
//
#include <hip/hip_runtime.h>
#include <math.h>

// ---------------- Workspace layout ----------------
// floats:   [0, 40960)        td accumulator (4096 x 10)
//           [40960, 81920)    Wtdr[tt][j][row][k] reordered W_td
//           [81920, 122880)   sc accumulator (4096 x 10)
// bytes:    [524288, +166*8192)  Bg: bf16 hi/lo B slabs in MFMA-fragment
//           order, Bg[s][plane][n][16k]; slab 8192 B; 162 real + pad slabs
#define TD_OFF 0
#define WTDR_OFF 40960
#define SC_OFF 81920
#define BG_BYTE_OFF 524288

typedef __bf16 bf16x8 __attribute__((ext_vector_type(8)));
typedef float f32x16 __attribute__((ext_vector_type(16)));
typedef float f32x2 __attribute__((ext_vector_type(2)));

union FragU { bf16x8 v; float4 f; };

__device__ __forceinline__ f32x16 mfma16(bf16x8 a, bf16x8 b, f32x16 c) {
    return __builtin_amdgcn_mfma_f32_32x32x16_bf16(a, b, c, 0, 0, 0);
}

__device__ __forceinline__ float eluf(float v) {
    return v > 0.f ? v : __expf(v) - 1.f;
}

// ---------------- prep: Wtdr reorder + Bg build ----------------------------
__global__ __launch_bounds__(256) void prep(const float* __restrict__ dw,
                                            const float* __restrict__ pw,
                                            const float* __restrict__ Wtd,
                                            float* __restrict__ Wtdr,
                                            unsigned short* __restrict__ Bg) {
    int gid = blockIdx.x * 256 + threadIdx.x;
    if (gid < 40960) {
        int k = gid & 3;
        int r = gid >> 2;
        int row = r & 31; r >>= 5;
        int j = r % 10;
        int tt = r / 10;
        Wtdr[gid] = Wtd[(size_t)(row * 128 + tt * 4 + k) * 10 + j];
        return;
    }
    int g2 = gid - 40960;
    if (g2 >= 162 * 128) return;
    int n = g2 & 127;
    int s = g2 >> 7;
    int half = s & 1;
    int cd = s >> 1;
    int c = cd / 27, d = cd % 27;
    int w = n >> 2, f = n & 3;
    unsigned short* dsth = Bg + (size_t)s * 4096 + n * 16;   // ushort units
    unsigned short* dstl = dsth + 2048;
#pragma unroll
    for (int k = 0; k < 16; k++) {
        int xi = half * 16 + k;
        int dx = xi - w + 13;
        float v = 0.f;
        if (dx >= 0 && dx < 27) {
#pragma unroll
            for (int m = 0; m < 5; m++)
                v = fmaf(dw[((d * 27 + dx) * 3 + c) * 5 + m],
                         pw[(c * 5 + m) * 4 + f], v);
        }
        __bf16 h = (__bf16)v;
        __bf16 l = (__bf16)(v - (float)h);
        dsth[k] = __builtin_bit_cast(unsigned short, h);
        dstl[k] = __builtin_bit_cast(unsigned short, l);
    }
}

// ---------------- fused: conv (MFMA pipe) + lstm (VALU pipe) co-scheduled --
// blockIdx % 5 == 4  -> lstm block (512 total)
// else               -> conv block (2048 total, 2 images each)
// I=2 images/block, launch_bounds(256,4): VGPR budget 128 fits the measured
// ~84-reg footprint WITHOUT spilling (r5's (256,5) cap of ~96 spilled the
// lstm branch -> 99MB scratch writes). LDS 24.9KB + VGPR 84 -> 4 blocks/CU
// = 16 waves/CU vs r4's LDS-capped 12. Conv loop identical to r5.
#define A_OFF 0
#define ZOFF 24576           /* 16 B zeros */
#define SRED_OFF 24592       /* 4 waves * 2 img * 10 floats = 320 B */
#define LDS_BYTES 24912

__global__ __launch_bounds__(256, 4) void fused(const float* __restrict__ x,
                                                const float* __restrict__ W,
                                                const float* __restrict__ U,
                                                const float* __restrict__ Wtdr,
                                                const unsigned short* __restrict__ Bg,
                                                const float* __restrict__ Wsc,
                                                const float* __restrict__ bias,
                                                float* __restrict__ td_out,
                                                float* __restrict__ sc_out) {
    __shared__ char LDS[LDS_BYTES] __attribute__((aligned(16)));
    int bx = blockIdx.x;
    int rem = bx % 5;
    int q = bx / 5;
    int t = threadIdx.x;

    if (rem == 4) {
        // ================= LSTM branch (block q in [0,512)) =================
        f32x2 sW0[8], sW1[8], sW2[8], sU0[8], sU1[8], sU2[8], sU3[8];
        const f32x2* Wp = (const f32x2*)W;
        const f32x2* Up = (const f32x2*)U;
#pragma unroll
        for (int k2 = 0; k2 < 8; k2++) {
            sW0[k2] = Wp[k2];
            sW1[k2] = Wp[8 + k2];
            sW2[k2] = Wp[16 + k2];
            sU0[k2] = Up[k2];
            sU1[k2] = Up[8 + k2];
            sU2[k2] = Up[16 + k2];
            sU3[k2] = Up[24 + k2];
        }

        int n = q * 256 + t;   // n = b*32 + row
        int row = n & 31;
        const float4* xp4 = (const float4*)(x + (size_t)n * 96);

        float h0 = 0, h1 = 0, h2 = 0, h3 = 0;
        float c0 = 0, c1 = 0, c2 = 0, c3 = 0;
        f32x2 pa2[10];
#pragma unroll
        for (int j = 0; j < 10; j++) pa2[j] = 0.f;

        for (int g = 0; g < 8; g++) {
            float4 q0 = xp4[g * 3 + 0], q1 = xp4[g * 3 + 1], q2 = xp4[g * 3 + 2];
            float xr[12] = {q0.x, q0.y, q0.z, q0.w, q1.x, q1.y,
                            q1.z, q1.w, q2.x, q2.y, q2.z, q2.w};
#pragma unroll
            for (int st = 0; st < 4; st++) {
                int tt = g * 4 + st;
                float x0 = xr[st * 3 + 0], x1 = xr[st * 3 + 1], x2 = xr[st * 3 + 2];
                f32x2 z2[8];
#pragma unroll
                for (int k2 = 0; k2 < 8; k2++)
                    z2[k2] = sW0[k2] * x0 + sW1[k2] * x1 + sW2[k2] * x2
                           + sU0[k2] * h0 + sU1[k2] * h1 + sU2[k2] * h2
                           + sU3[k2] * h3;

                float ig0 = eluf(z2[0][0]), ig1 = eluf(z2[0][1]);
                float ig2 = eluf(z2[1][0]), ig3 = eluf(z2[1][1]);
                float fg0 = eluf(z2[2][0]), fg1 = eluf(z2[2][1]);
                float fg2 = eluf(z2[3][0]), fg3 = eluf(z2[3][1]);
                float og0 = eluf(z2[6][0]), og1 = eluf(z2[6][1]);
                float og2 = eluf(z2[7][0]), og3 = eluf(z2[7][1]);

                float zc0 = z2[4][0], zc1 = z2[4][1], zc2 = z2[5][0], zc3 = z2[5][1];
                float zm = fmaxf(fmaxf(zc0, zc1), fmaxf(zc2, zc3));
                float e0 = __expf(zc0 - zm), e1 = __expf(zc1 - zm);
                float e2 = __expf(zc2 - zm), e3 = __expf(zc3 - zm);
                float inv = 1.f / (e0 + e1 + e2 + e3);
                c0 = fg0 * c0 + ig0 * (e0 * inv);
                c1 = fg1 * c1 + ig1 * (e1 * inv);
                c2 = fg2 * c2 + ig2 * (e2 * inv);
                c3 = fg3 * c3 + ig3 * (e3 * inv);

                float cm = fmaxf(fmaxf(c0, c1), fmaxf(c2, c3));
                float p0 = __expf(c0 - cm), p1 = __expf(c1 - cm);
                float p2 = __expf(c2 - cm), p3 = __expf(c3 - cm);
                float pinv = 1.f / (p0 + p1 + p2 + p3);
                h0 = og0 * (p0 * pinv); h1 = og1 * (p1 * pinv);
                h2 = og2 * (p2 * pinv); h3 = og3 * (p3 * pinv);

                const f32x2* wr2 = (const f32x2*)(Wtdr + (size_t)tt * 1280) + row * 2;
                f32x2 h01 = {h0, h1}, h23 = {h2, h3};
#pragma unroll
                for (int j = 0; j < 10; j++)
                    pa2[j] += h01 * wr2[j * 64] + h23 * wr2[j * 64 + 1];
            }
        }

        float acc[10];
#pragma unroll
        for (int j = 0; j < 10; j++) acc[j] = pa2[j][0] + pa2[j][1];
#pragma unroll
        for (int off = 16; off >= 1; off >>= 1) {
#pragma unroll
            for (int j = 0; j < 10; j++) acc[j] += __shfl_xor(acc[j], off, 64);
        }
        int lane = t & 63;
        if (lane == 0 || lane == 32) {
            int b = n >> 5;
#pragma unroll
            for (int j = 0; j < 10; j++) td_out[b * 10 + j] = acc[j];
        }
        return;
    }

    // ================= conv branch (ci in [0,2048), 2 images) ==============
    int ci = q * 4 + rem;
    int l = t & 63;
    int wv = t >> 6;           // wave owns ntile = wv, both images
    int m = l & 31;
    int sub = l >> 5;          // k-subgroup (8 k's each)

    const char* bbase = (const char*)Bg + (size_t)wv * 1024 + m * 32 + sub * 16;
    FragU bufA[2], bufB[2], bufC[2];
#define LOADB(sv, arr) { const char* p_ = bbase + (size_t)(sv) * 8192;       \
        arr[0].f = *(const float4*)(p_);          /* hi */                   \
        arr[1].f = *(const float4*)(p_ + 4096); } /* lo */

    LOADB(0, bufA);
    LOADB(1, bufB);
    LOADB(2, bufC);

    // ---- stage A: thread <-> (img, w-oct, h); b128 writes, conflict-free --
    const float* xb = x + (size_t)ci * 6144;
    {
        int u = t;                       // 256 units: 2 img x 4 woct x 32 h
        int im = u >> 7;
        int woct = (u >> 5) & 3;
        int h = u & 31;
        const float4* src = (const float4*)(xb + im * 3072 + h * 96 + woct * 24);
        float xr[24];
#pragma unroll
        for (int i = 0; i < 6; i++) {
            float4 qv = src[i];
            xr[i * 4 + 0] = qv.x; xr[i * 4 + 1] = qv.y;
            xr[i * 4 + 2] = qv.z; xr[i * 4 + 3] = qv.w;
        }
#pragma unroll
        for (int cc = 0; cc < 3; cc++) {
            FragU hiF, loF;
#pragma unroll
            for (int k = 0; k < 8; k++) {
                float v = xr[k * 3 + cc];
                __bf16 hb = (__bf16)v;
                hiF.v[k] = hb;
                loF.v[k] = (__bf16)(v - (float)hb);
            }
            int rec = A_OFF + im * 12288 + (cc * 8 + woct) * 512 + h * 16;
            *(float4*)(LDS + rec) = hiF.f;
            *(float4*)(LDS + rec + 2048) = loF.f;
        }
    }
    if (t < 4) *(float*)(LDS + ZOFF + t * 4) = 0.f;
    __syncthreads();   // the only barrier before the epilogue

    f32x16 acc0 = {0,0,0,0,0,0,0,0,0,0,0,0,0,0,0,0};
    f32x16 acc1 = acc0;

    int c = 0, d = 0, half = 0;

#define CHUNK(USE, SNEXT) {                                                   \
    int rowIdx = m + d - 13;                                                  \
    bool valid = (unsigned)rowIdx < 32u;                                      \
    int a0 = A_OFF + (c * 8 + half * 2 + sub) * 512 + rowIdx * 16;            \
    FragU ah0, ah1, al0, al1;                                                 \
    ah0.f = *(const float4*)(LDS + (valid ? a0           : ZOFF));            \
    ah1.f = *(const float4*)(LDS + (valid ? a0 + 12288   : ZOFF));            \
    al0.f = *(const float4*)(LDS + (valid ? a0 + 2048    : ZOFF));            \
    al1.f = *(const float4*)(LDS + (valid ? a0 + 14336   : ZOFF));            \
    acc0 = mfma16(ah0.v, USE[0].v, acc0);                                     \
    acc1 = mfma16(ah1.v, USE[0].v, acc1);                                     \
    acc0 = mfma16(ah0.v, USE[1].v, acc0);                                     \
    acc1 = mfma16(ah1.v, USE[1].v, acc1);                                     \
    acc0 = mfma16(al0.v, USE[0].v, acc0);                                     \
    acc1 = mfma16(al1.v, USE[0].v, acc1);                                     \
    LOADB(SNEXT, USE);                                                        \
    half ^= 1;                                                                \
    if (!half) { d++; if (d == 27) { d = 0; c++; } }                          \
}

    for (int g = 0; g < 54; g++) {
        CHUNK(bufA, 3 * g + 3);
        CHUNK(bufB, 3 * g + 4);
        CHUNK(bufC, 3 * g + 5);
    }

    // ---- epilogue: bias + sigmoid + W_sc partial dot (rows reused x2) ----
    float b4[4];
#pragma unroll
    for (int i = 0; i < 4; i++) b4[i] = bias[i];

    float part[2][10];
#pragma unroll
    for (int i = 0; i < 2; i++)
#pragma unroll
        for (int j = 0; j < 10; j++) part[i][j] = 0.f;

    f32x16 accs[2] = {acc0, acc1};
    int ncol = wv * 32 + m;
    int wcol = ncol >> 2;
    int f = ncol & 3;
#pragma unroll
    for (int r = 0; r < 16; r++) {
        int h = (r & 3) + 8 * (r >> 2) + 4 * sub;
        const float* wr = Wsc + (size_t)((h * 32 + wcol) * 4 + f) * 10;
        float wreg[10];
#pragma unroll
        for (int j = 0; j < 10; j++) wreg[j] = wr[j];
#pragma unroll
        for (int im = 0; im < 2; im++) {
            float v = accs[im][r] + b4[f];
            float sg = 1.f / (1.f + __expf(-v));
#pragma unroll
            for (int j = 0; j < 10; j++) part[im][j] = fmaf(sg, wreg[j], part[im][j]);
        }
    }

#pragma unroll
    for (int off = 32; off >= 1; off >>= 1) {
#pragma unroll
        for (int im = 0; im < 2; im++)
#pragma unroll
            for (int j = 0; j < 10; j++) part[im][j] += __shfl_xor(part[im][j], off, 64);
    }
    if (l == 0) {
        float* red = (float*)(LDS + SRED_OFF);
#pragma unroll
        for (int im = 0; im < 2; im++)
#pragma unroll
            for (int j = 0; j < 10; j++) red[(wv * 2 + im) * 10 + j] = part[im][j];
    }
    __syncthreads();
    if (t < 20) {
        int img = t / 10, j = t % 10;
        const float* red = (const float*)(LDS + SRED_OFF);
        float sv = red[(0 * 2 + img) * 10 + j] + red[(1 * 2 + img) * 10 + j]
                 + red[(2 * 2 + img) * 10 + j] + red[(3 * 2 + img) * 10 + j];
        sc_out[(ci * 2 + img) * 10 + j] = sv;
    }
}

// ---------------- compare: |td - sc| <= atol + rtol*|sc| -------------------
__global__ __launch_bounds__(256) void cmp_k(const float* __restrict__ td,
                                             const float* __restrict__ sc,
                                             float* __restrict__ out) {
    int i = blockIdx.x * 256 + threadIdx.x;
    if (i < 40960) {
        float a = td[i];
        float s = sc[i];
        float tol = 1e-6f + 1e-6f * fabsf(s);
        out[i] = (fabsf(a - s) <= tol) ? 1.0f : 0.0f;
    }
}

extern "C" void kernel_launch(void* const* d_in, const int* in_sizes, int n_in,
                              void* d_out, int out_size, void* d_ws, size_t ws_size,
                              hipStream_t stream) {
    const float* x    = (const float*)d_in[0];
    const float* W    = (const float*)d_in[1];
    const float* U    = (const float*)d_in[2];
    const float* dw   = (const float*)d_in[3];
    const float* pw   = (const float*)d_in[4];
    const float* bias = (const float*)d_in[5];
    const float* Wtd  = (const float*)d_in[6];
    const float* Wsc  = (const float*)d_in[7];

    float* ws     = (float*)d_ws;
    float* td_acc = ws + TD_OFF;
    float* Wtdr   = ws + WTDR_OFF;
    float* sc_acc = ws + SC_OFF;
    unsigned short* Bg = (unsigned short*)((char*)d_ws + BG_BYTE_OFF);

    prep<<<241, 256, 0, stream>>>(dw, pw, Wtd, Wtdr, Bg);
    fused<<<2560, 256, 0, stream>>>(x, W, U, Wtdr, Bg, Wsc, bias, td_acc, sc_acc);
    cmp_k<<<160, 256, 0, stream>>>(td_acc, sc_acc, (float*)d_out);
}

// Round 7
// 352.937 us; speedup vs baseline: 1.1556x; 1.1153x over previous
//
#include <hip/hip_runtime.h>
#include <math.h>

// ---------------- Workspace layout ----------------
// floats:   [0, 40960)        td accumulator (4096 x 10)
//           [40960, 81920)    Wtdr[tt][j][row][k] reordered W_td
//           [81920, 122880)   sc accumulator (4096 x 10)
// bytes:    [524288, +166*8192)  Bg: bf16 hi/lo B slabs in MFMA-fragment
//           order, Bg[s][plane][n][16k]; slab 8192 B; 162 real + pad slabs
#define TD_OFF 0
#define WTDR_OFF 40960
#define SC_OFF 81920
#define BG_BYTE_OFF 524288

typedef __bf16 bf16x8 __attribute__((ext_vector_type(8)));
typedef float f32x16 __attribute__((ext_vector_type(16)));
typedef float f32x2 __attribute__((ext_vector_type(2)));

union FragU { bf16x8 v; float4 f; };

__device__ __forceinline__ f32x16 mfma16(bf16x8 a, bf16x8 b, f32x16 c) {
    return __builtin_amdgcn_mfma_f32_32x32x16_bf16(a, b, c, 0, 0, 0);
}

__device__ __forceinline__ float eluf(float v) {
    return v > 0.f ? v : __expf(v) - 1.f;
}

// ---------------- prep: Wtdr reorder + Bg build ----------------------------
__global__ __launch_bounds__(256) void prep(const float* __restrict__ dw,
                                            const float* __restrict__ pw,
                                            const float* __restrict__ Wtd,
                                            float* __restrict__ Wtdr,
                                            unsigned short* __restrict__ Bg) {
    int gid = blockIdx.x * 256 + threadIdx.x;
    if (gid < 40960) {
        int k = gid & 3;
        int r = gid >> 2;
        int row = r & 31; r >>= 5;
        int j = r % 10;
        int tt = r / 10;
        Wtdr[gid] = Wtd[(size_t)(row * 128 + tt * 4 + k) * 10 + j];
        return;
    }
    int g2 = gid - 40960;
    if (g2 >= 162 * 128) return;
    int n = g2 & 127;
    int s = g2 >> 7;
    int half = s & 1;
    int cd = s >> 1;
    int c = cd / 27, d = cd % 27;
    int w = n >> 2, f = n & 3;
    unsigned short* dsth = Bg + (size_t)s * 4096 + n * 16;   // ushort units
    unsigned short* dstl = dsth + 2048;
#pragma unroll
    for (int k = 0; k < 16; k++) {
        int xi = half * 16 + k;
        int dx = xi - w + 13;
        float v = 0.f;
        if (dx >= 0 && dx < 27) {
#pragma unroll
            for (int m = 0; m < 5; m++)
                v = fmaf(dw[((d * 27 + dx) * 3 + c) * 5 + m],
                         pw[(c * 5 + m) * 4 + f], v);
        }
        __bf16 h = (__bf16)v;
        __bf16 l = (__bf16)(v - (float)h);
        dsth[k] = __builtin_bit_cast(unsigned short, h);
        dstl[k] = __builtin_bit_cast(unsigned short, l);
    }
}

// ---------------- fused: conv (MFMA pipe) + lstm (VALU pipe) co-scheduled --
// blockIdx % 3 == 2  -> lstm block (512 total)
// blockIdx % 3 in{0,1} -> conv block (1024 total, 4 images)
// DOUBLE-CHUNK inner loop: per iteration a wave processes BOTH K-halves of
// one (c,d): 24 MFMA + 16 ds_read sharing ONE rowIdx/valid computation and
// one B slab-pair fetch. Halves per-MFMA VALU overhead vs r4 (the only
// lever that has tracked perf across r1/r2/r4/r6: MFMA density per chunk).
// Precision scheme (bf16 hi/lo, 3 products) untouched: error math says
// single-plane would flip ~8 booleans. Partition/staging/epilogue = r4.
#define A_OFF 0
#define ZOFF 49152           /* 16 B zeros */
#define SRED_OFF 49168       /* 4 waves * 4 img * 10 floats = 640 B */
#define LDS_BYTES 49808

__global__ __launch_bounds__(256, 3) void fused(const float* __restrict__ x,
                                                const float* __restrict__ W,
                                                const float* __restrict__ U,
                                                const float* __restrict__ Wtdr,
                                                const unsigned short* __restrict__ Bg,
                                                const float* __restrict__ Wsc,
                                                const float* __restrict__ bias,
                                                float* __restrict__ td_out,
                                                float* __restrict__ sc_out) {
    __shared__ char LDS[LDS_BYTES] __attribute__((aligned(16)));
    int bx = blockIdx.x;
    int rem = bx % 3;
    int q = bx / 3;
    int t = threadIdx.x;

    if (rem == 2) {
        // ================= LSTM branch (block q in [0,512)) =================
        f32x2 sW0[8], sW1[8], sW2[8], sU0[8], sU1[8], sU2[8], sU3[8];
        const f32x2* Wp = (const f32x2*)W;
        const f32x2* Up = (const f32x2*)U;
#pragma unroll
        for (int k2 = 0; k2 < 8; k2++) {
            sW0[k2] = Wp[k2];
            sW1[k2] = Wp[8 + k2];
            sW2[k2] = Wp[16 + k2];
            sU0[k2] = Up[k2];
            sU1[k2] = Up[8 + k2];
            sU2[k2] = Up[16 + k2];
            sU3[k2] = Up[24 + k2];
        }

        int n = q * 256 + t;   // n = b*32 + row
        int row = n & 31;
        const float4* xp4 = (const float4*)(x + (size_t)n * 96);

        float h0 = 0, h1 = 0, h2 = 0, h3 = 0;
        float c0 = 0, c1 = 0, c2 = 0, c3 = 0;
        f32x2 pa2[10];
#pragma unroll
        for (int j = 0; j < 10; j++) pa2[j] = 0.f;

        for (int g = 0; g < 8; g++) {
            float4 q0 = xp4[g * 3 + 0], q1 = xp4[g * 3 + 1], q2 = xp4[g * 3 + 2];
            float xr[12] = {q0.x, q0.y, q0.z, q0.w, q1.x, q1.y,
                            q1.z, q1.w, q2.x, q2.y, q2.z, q2.w};
#pragma unroll
            for (int st = 0; st < 4; st++) {
                int tt = g * 4 + st;
                float x0 = xr[st * 3 + 0], x1 = xr[st * 3 + 1], x2 = xr[st * 3 + 2];
                f32x2 z2[8];
#pragma unroll
                for (int k2 = 0; k2 < 8; k2++)
                    z2[k2] = sW0[k2] * x0 + sW1[k2] * x1 + sW2[k2] * x2
                           + sU0[k2] * h0 + sU1[k2] * h1 + sU2[k2] * h2
                           + sU3[k2] * h3;

                float ig0 = eluf(z2[0][0]), ig1 = eluf(z2[0][1]);
                float ig2 = eluf(z2[1][0]), ig3 = eluf(z2[1][1]);
                float fg0 = eluf(z2[2][0]), fg1 = eluf(z2[2][1]);
                float fg2 = eluf(z2[3][0]), fg3 = eluf(z2[3][1]);
                float og0 = eluf(z2[6][0]), og1 = eluf(z2[6][1]);
                float og2 = eluf(z2[7][0]), og3 = eluf(z2[7][1]);

                float zc0 = z2[4][0], zc1 = z2[4][1], zc2 = z2[5][0], zc3 = z2[5][1];
                float zm = fmaxf(fmaxf(zc0, zc1), fmaxf(zc2, zc3));
                float e0 = __expf(zc0 - zm), e1 = __expf(zc1 - zm);
                float e2 = __expf(zc2 - zm), e3 = __expf(zc3 - zm);
                float inv = 1.f / (e0 + e1 + e2 + e3);
                c0 = fg0 * c0 + ig0 * (e0 * inv);
                c1 = fg1 * c1 + ig1 * (e1 * inv);
                c2 = fg2 * c2 + ig2 * (e2 * inv);
                c3 = fg3 * c3 + ig3 * (e3 * inv);

                float cm = fmaxf(fmaxf(c0, c1), fmaxf(c2, c3));
                float p0 = __expf(c0 - cm), p1 = __expf(c1 - cm);
                float p2 = __expf(c2 - cm), p3 = __expf(c3 - cm);
                float pinv = 1.f / (p0 + p1 + p2 + p3);
                h0 = og0 * (p0 * pinv); h1 = og1 * (p1 * pinv);
                h2 = og2 * (p2 * pinv); h3 = og3 * (p3 * pinv);

                const f32x2* wr2 = (const f32x2*)(Wtdr + (size_t)tt * 1280) + row * 2;
                f32x2 h01 = {h0, h1}, h23 = {h2, h3};
#pragma unroll
                for (int j = 0; j < 10; j++)
                    pa2[j] += h01 * wr2[j * 64] + h23 * wr2[j * 64 + 1];
            }
        }

        float acc[10];
#pragma unroll
        for (int j = 0; j < 10; j++) acc[j] = pa2[j][0] + pa2[j][1];
#pragma unroll
        for (int off = 16; off >= 1; off >>= 1) {
#pragma unroll
            for (int j = 0; j < 10; j++) acc[j] += __shfl_xor(acc[j], off, 64);
        }
        int lane = t & 63;
        if (lane == 0 || lane == 32) {
            int b = n >> 5;
#pragma unroll
            for (int j = 0; j < 10; j++) td_out[b * 10 + j] = acc[j];
        }
        return;
    }

    // ================= conv branch (ci in [0,1024), 4 images) ==============
    int ci = q * 2 + rem;
    int l = t & 63;
    int wv = t >> 6;           // wave owns ntile = wv, all 4 images
    int m = l & 31;
    int sub = l >> 5;          // k-subgroup (8 k's each)

    // B double-slab base: pair D covers slabs 2D (half0) and 2D+1 (half1),
    // 16384 B apart-stride; within slab: hi +0, lo +4096.
    const char* bbase = (const char*)Bg + (size_t)wv * 1024 + m * 32 + sub * 16;
    FragU bA[4], bB[4];
#define LOADB2(OFF, arr) { const char* p_ = bbase + (OFF);                   \
        arr[0].f = *(const float4*)(p_);           /* h0 hi */               \
        arr[1].f = *(const float4*)(p_ + 4096);    /* h0 lo */               \
        arr[2].f = *(const float4*)(p_ + 8192);    /* h1 hi */               \
        arr[3].f = *(const float4*)(p_ + 12288); } /* h1 lo */

    LOADB2(0, bA);
    LOADB2(16384, bB);
    int boff = 2 * 16384;

    // ---- stage A: thread <-> (img, w-oct, h); b128 writes, conflict-free --
    const float* xb = x + (size_t)ci * 12288;
#pragma unroll
    for (int rep = 0; rep < 2; rep++) {
        int u = rep * 256 + t;           // 512 units: 4 img x 4 woct x 32 h
        int im = u >> 7;
        int woct = (u >> 5) & 3;
        int h = u & 31;
        const float4* src = (const float4*)(xb + im * 3072 + h * 96 + woct * 24);
        float xr[24];
#pragma unroll
        for (int i = 0; i < 6; i++) {
            float4 qv = src[i];
            xr[i * 4 + 0] = qv.x; xr[i * 4 + 1] = qv.y;
            xr[i * 4 + 2] = qv.z; xr[i * 4 + 3] = qv.w;
        }
#pragma unroll
        for (int cc = 0; cc < 3; cc++) {
            FragU hiF, loF;
#pragma unroll
            for (int k = 0; k < 8; k++) {
                float v = xr[k * 3 + cc];
                __bf16 hb = (__bf16)v;
                hiF.v[k] = hb;
                loF.v[k] = (__bf16)(v - (float)hb);
            }
            int rec = A_OFF + im * 12288 + (cc * 8 + woct) * 512 + h * 16;
            *(float4*)(LDS + rec) = hiF.f;
            *(float4*)(LDS + rec + 2048) = loF.f;
        }
    }
    if (t < 4) *(float*)(LDS + ZOFF + t * 4) = 0.f;
    __syncthreads();   // the only barrier before the epilogue

    f32x16 acc0 = {0,0,0,0,0,0,0,0,0,0,0,0,0,0,0,0};
    f32x16 acc1 = acc0, acc2 = acc0, acc3 = acc0;

    int c = 0, d = 0;

    // Per img at base A: h0hi=+0, h0lo=+2048, h1hi=+1024, h1lo=+3072.
    // Img strides 12288. One rowIdx/valid for all 16 reads and 24 MFMAs.
#define DCHUNK(BUF, DOLOAD) {                                                 \
    int rowIdx = m + d - 13;                                                  \
    bool valid = (unsigned)rowIdx < 32u;                                      \
    int a0 = A_OFF + (c * 8 + sub) * 512 + rowIdx * 16;                       \
    FragU f0h, f0l, f1h, f1l, g0h, g0l, g1h, g1l;                             \
    f0h.f = *(const float4*)(LDS + (valid ? a0          : ZOFF));             \
    f0l.f = *(const float4*)(LDS + (valid ? a0 + 2048   : ZOFF));             \
    f1h.f = *(const float4*)(LDS + (valid ? a0 + 1024   : ZOFF));             \
    f1l.f = *(const float4*)(LDS + (valid ? a0 + 3072   : ZOFF));             \
    g0h.f = *(const float4*)(LDS + (valid ? a0 + 12288  : ZOFF));             \
    g0l.f = *(const float4*)(LDS + (valid ? a0 + 14336  : ZOFF));             \
    g1h.f = *(const float4*)(LDS + (valid ? a0 + 13312  : ZOFF));             \
    g1l.f = *(const float4*)(LDS + (valid ? a0 + 15360  : ZOFF));             \
    acc0 = mfma16(f0h.v, BUF[0].v, acc0);                                     \
    acc1 = mfma16(g0h.v, BUF[0].v, acc1);                                     \
    acc0 = mfma16(f1h.v, BUF[2].v, acc0);                                     \
    acc1 = mfma16(g1h.v, BUF[2].v, acc1);                                     \
    acc0 = mfma16(f0h.v, BUF[1].v, acc0);                                     \
    acc1 = mfma16(g0h.v, BUF[1].v, acc1);                                     \
    acc0 = mfma16(f1h.v, BUF[3].v, acc0);                                     \
    acc1 = mfma16(g1h.v, BUF[3].v, acc1);                                     \
    acc0 = mfma16(f0l.v, BUF[0].v, acc0);                                     \
    acc1 = mfma16(g0l.v, BUF[0].v, acc1);                                     \
    acc0 = mfma16(f1l.v, BUF[2].v, acc0);                                     \
    acc1 = mfma16(g1l.v, BUF[2].v, acc1);                                     \
    if (DOLOAD) { LOADB2(boff, BUF); boff += 16384; }                         \
    f0h.f = *(const float4*)(LDS + (valid ? a0 + 24576  : ZOFF));             \
    f0l.f = *(const float4*)(LDS + (valid ? a0 + 26624  : ZOFF));             \
    f1h.f = *(const float4*)(LDS + (valid ? a0 + 25600  : ZOFF));             \
    f1l.f = *(const float4*)(LDS + (valid ? a0 + 27648  : ZOFF));             \
    g0h.f = *(const float4*)(LDS + (valid ? a0 + 36864  : ZOFF));             \
    g0l.f = *(const float4*)(LDS + (valid ? a0 + 38912  : ZOFF));             \
    g1h.f = *(const float4*)(LDS + (valid ? a0 + 37888  : ZOFF));             \
    g1l.f = *(const float4*)(LDS + (valid ? a0 + 39936  : ZOFF));             \
    acc2 = mfma16(f0h.v, BUF[0].v, acc2);                                     \
    acc3 = mfma16(g0h.v, BUF[0].v, acc3);                                     \
    acc2 = mfma16(f1h.v, BUF[2].v, acc2);                                     \
    acc3 = mfma16(g1h.v, BUF[2].v, acc3);                                     \
    acc2 = mfma16(f0h.v, BUF[1].v, acc2);                                     \
    acc3 = mfma16(g0h.v, BUF[1].v, acc3);                                     \
    acc2 = mfma16(f1h.v, BUF[3].v, acc2);                                     \
    acc3 = mfma16(g1h.v, BUF[3].v, acc3);                                     \
    acc2 = mfma16(f0l.v, BUF[0].v, acc2);                                     \
    acc3 = mfma16(g0l.v, BUF[0].v, acc3);                                     \
    acc2 = mfma16(f1l.v, BUF[2].v, acc2);                                     \
    acc3 = mfma16(g1l.v, BUF[2].v, acc3);                                     \
    d++; if (d == 27) { d = 0; c++; }                                         \
}

    for (int g = 0; g < 40; g++) {
        DCHUNK(bA, 1);
        DCHUNK(bB, 1);
    }
    DCHUNK(bA, 0);   // 81st double-chunk (D=80); bB's D=81 unused

    // ---- epilogue: bias + sigmoid + W_sc partial dot (rows reused x4) ----
    float b4[4];
#pragma unroll
    for (int i = 0; i < 4; i++) b4[i] = bias[i];

    float part[4][10];
#pragma unroll
    for (int i = 0; i < 4; i++)
#pragma unroll
        for (int j = 0; j < 10; j++) part[i][j] = 0.f;

    f32x16 accs[4] = {acc0, acc1, acc2, acc3};
    int ncol = wv * 32 + m;
    int wcol = ncol >> 2;
    int f = ncol & 3;
#pragma unroll
    for (int r = 0; r < 16; r++) {
        int h = (r & 3) + 8 * (r >> 2) + 4 * sub;
        const float* wr = Wsc + (size_t)((h * 32 + wcol) * 4 + f) * 10;
        float wreg[10];
#pragma unroll
        for (int j = 0; j < 10; j++) wreg[j] = wr[j];
#pragma unroll
        for (int im = 0; im < 4; im++) {
            float v = accs[im][r] + b4[f];
            float sg = 1.f / (1.f + __expf(-v));
#pragma unroll
            for (int j = 0; j < 10; j++) part[im][j] = fmaf(sg, wreg[j], part[im][j]);
        }
    }

#pragma unroll
    for (int off = 32; off >= 1; off >>= 1) {
#pragma unroll
        for (int im = 0; im < 4; im++)
#pragma unroll
            for (int j = 0; j < 10; j++) part[im][j] += __shfl_xor(part[im][j], off, 64);
    }
    if (l == 0) {
        float* red = (float*)(LDS + SRED_OFF);
#pragma unroll
        for (int im = 0; im < 4; im++)
#pragma unroll
            for (int j = 0; j < 10; j++) red[(wv * 4 + im) * 10 + j] = part[im][j];
    }
    __syncthreads();
    if (t < 40) {
        int img = t / 10, j = t % 10;
        const float* red = (const float*)(LDS + SRED_OFF);
        float sv = red[(0 * 4 + img) * 10 + j] + red[(1 * 4 + img) * 10 + j]
                 + red[(2 * 4 + img) * 10 + j] + red[(3 * 4 + img) * 10 + j];
        sc_out[(ci * 4 + img) * 10 + j] = sv;
    }
}

// ---------------- compare: |td - sc| <= atol + rtol*|sc| -------------------
__global__ __launch_bounds__(256) void cmp_k(const float* __restrict__ td,
                                             const float* __restrict__ sc,
                                             float* __restrict__ out) {
    int i = blockIdx.x * 256 + threadIdx.x;
    if (i < 40960) {
        float a = td[i];
        float s = sc[i];
        float tol = 1e-6f + 1e-6f * fabsf(s);
        out[i] = (fabsf(a - s) <= tol) ? 1.0f : 0.0f;
    }
}

extern "C" void kernel_launch(void* const* d_in, const int* in_sizes, int n_in,
                              void* d_out, int out_size, void* d_ws, size_t ws_size,
                              hipStream_t stream) {
    const float* x    = (const float*)d_in[0];
    const float* W    = (const float*)d_in[1];
    const float* U    = (const float*)d_in[2];
    const float* dw   = (const float*)d_in[3];
    const float* pw   = (const float*)d_in[4];
    const float* bias = (const float*)d_in[5];
    const float* Wtd  = (const float*)d_in[6];
    const float* Wsc  = (const float*)d_in[7];

    float* ws     = (float*)d_ws;
    float* td_acc = ws + TD_OFF;
    float* Wtdr   = ws + WTDR_OFF;
    float* sc_acc = ws + SC_OFF;
    unsigned short* Bg = (unsigned short*)((char*)d_ws + BG_BYTE_OFF);

    prep<<<241, 256, 0, stream>>>(dw, pw, Wtd, Wtdr, Bg);
    fused<<<1536, 256, 0, stream>>>(x, W, U, Wtdr, Bg, Wsc, bias, td_acc, sc_acc);
    cmp_k<<<160, 256, 0, stream>>>(td_acc, sc_acc, (float*)d_out);
}